// Round 4
// baseline (382.799 us; speedup 1.0000x reference)
//
#include <hip/hip_runtime.h>

// Problem constants (from reference setup_inputs)
#define BZ 4
#define H 192
#define W 640
#define PIX (H * W)            // 122880 pixels per batch
#define MAXINS 200
#define CAND 16
#define CE 36                  // ch*cw
#define CE4 9                  // float4 groups per pixel

// K1: comp[b,m,:] = selsrc[b, m, batchidx[b,m], :]
// (folds the +sel term into the accumulator init; also re-inits ws every call)
__global__ void init_sel_kernel(const int* __restrict__ batchidx,
                                const float4* __restrict__ selsrc,
                                float4* __restrict__ comp) {
    unsigned t = blockIdx.x * blockDim.x + threadIdx.x;   // over BZ*MAXINS*CE4 = 7200
    const unsigned total = BZ * MAXINS * CE4;
    if (t >= total) return;
    unsigned e4 = t % CE4;
    unsigned bm = t / CE4;                 // b*MAXINS + m
    int c = batchidx[bm];                  // in [0, CAND)
    comp[bm * CE4 + e4] = selsrc[(bm * CAND + (unsigned)c) * CE4 + e4];
}

// K2: comp[b, idx[pix], :] += compsrc[pix, :]   (atomic segment-sum)
__global__ void compress_kernel(const int* __restrict__ inst,
                                const float4* __restrict__ compsrc,
                                float* __restrict__ comp) {
    const unsigned total = BZ * PIX * CE4;                // 4,423,680
    for (unsigned t = blockIdx.x * blockDim.x + threadIdx.x; t < total;
         t += gridDim.x * blockDim.x) {
        unsigned e4 = t % CE4;
        unsigned pix = t / CE4;
        unsigned b = pix / PIX;
        int m = inst[pix];                                // broadcast across 9 lanes
        float4 v = compsrc[t];                            // coalesced 16B/lane
        float* dst = comp + ((unsigned)(b * MAXINS + m)) * CE + e4 * 4;
        atomicAdd(dst + 0, v.x);
        atomicAdd(dst + 1, v.y);
        atomicAdd(dst + 2, v.z);
        atomicAdd(dst + 3, v.w);
    }
}

// K3: out[pix, :] = comp[b, idx[pix], :]
__global__ void inflate_kernel(const int* __restrict__ inst,
                               const float4* __restrict__ comp,
                               float4* __restrict__ out) {
    const unsigned total = BZ * PIX * CE4;
    for (unsigned t = blockIdx.x * blockDim.x + threadIdx.x; t < total;
         t += gridDim.x * blockDim.x) {
        unsigned e4 = t % CE4;
        unsigned pix = t / CE4;
        unsigned b = pix / PIX;
        int m = inst[pix];
        out[t] = comp[((unsigned)(b * MAXINS + m)) * CE4 + e4];  // L2-hot gather
    }
}

extern "C" void kernel_launch(void* const* d_in, const int* in_sizes, int n_in,
                              void* d_out, int out_size, void* d_ws, size_t ws_size,
                              hipStream_t stream) {
    const int*    inst     = (const int*)d_in[0];      // (BZ,1,H,W) int32
    const float*  compsrc  = (const float*)d_in[1];    // (BZ,H,W,6,6) f32
    const int*    batchidx = (const int*)d_in[2];      // (BZ,MAXINS) int32
    const float*  selsrc   = (const float*)d_in[3];    // (BZ,MAXINS,CAND,6,6) f32
    float*        out      = (float*)d_out;            // (BZ,H,W,6,6) f32
    float*        comp     = (float*)d_ws;             // BZ*MAXINS*CE floats = 115.2 KB

    // K1: init accumulator with the sel term (runs every call; ws not re-poisoned)
    {
        const int total = BZ * MAXINS * CE4;           // 7200
        const int block = 256;
        init_sel_kernel<<<(total + block - 1) / block, block, 0, stream>>>(
            batchidx, (const float4*)selsrc, (float4*)comp);
    }

    // K2: atomic segment-sum of compsrc into comp
    {
        const int block = 256;
        const int grid = 2048;                          // grid-stride, ~8.4 iters/thread
        compress_kernel<<<grid, block, 0, stream>>>(inst, (const float4*)compsrc, comp);
    }

    // K3: inflate comp back to per-pixel output
    {
        const int block = 256;
        const int grid = 2048;
        inflate_kernel<<<grid, block, 0, stream>>>(inst, (const float4*)comp, (float4*)out);
    }
}

// Round 6
// 126.417 us; speedup vs baseline: 3.0281x; 3.0281x over previous
//
#include <hip/hip_runtime.h>

// Problem constants (from reference setup_inputs)
#define BZ 4
#define H 192
#define W 640
#define PIX (H * W)            // 122880 pixels per batch
#define MAXINS 200
#define CAND 16
#define CE 36                  // ch*cw
#define CE4 9                  // float4 groups per pixel
#define COMP_FLOATS (BZ * MAXINS * CE)      // 28800 floats
#define COMP_BYTES  (COMP_FLOATS * 4)       // 115200 bytes
#define BPB 64                              // blocks per batch for compress
#define NBLK (BZ * BPB)                     // 256 compress blocks

// ---- shared helpers ----------------------------------------------------

__global__ void zero_kernel(float4* __restrict__ p, int n4) {
    for (int t = blockIdx.x * blockDim.x + threadIdx.x; t < n4;
         t += gridDim.x * blockDim.x)
        p[t] = make_float4(0.f, 0.f, 0.f, 0.f);
}

// ---- main path: LDS pre-aggregation + replicated flush -----------------

// Each block owns one batch b and a private LDS copy of comp[b];
// flushes with global atomics into shadow copy (blockIdx % R).
__global__ void compress_lds_kernel(const int* __restrict__ inst,
                                    const float4* __restrict__ compsrc,
                                    float* __restrict__ shadows, int R) {
    __shared__ float lcomp[MAXINS * CE];   // 28.8 KB
    for (int i = threadIdx.x; i < MAXINS * CE; i += blockDim.x) lcomp[i] = 0.f;
    __syncthreads();

    const int b   = blockIdx.x / BPB;
    const int blk = blockIdx.x % BPB;

    for (int p = blk * blockDim.x + threadIdx.x; p < PIX; p += BPB * blockDim.x) {
        const int m = inst[b * PIX + p];
        const float4* src = compsrc + (size_t)(b * PIX + p) * CE4;
        float* dst = lcomp + m * CE;
        #pragma unroll
        for (int e = 0; e < CE4; ++e) {
            float4 v = src[e];               // 9 independent loads -> ILP
            atomicAdd(dst + e * 4 + 0, v.x); // ds_add_f32 (CU-local)
            atomicAdd(dst + e * 4 + 1, v.y);
            atomicAdd(dst + e * 4 + 2, v.z);
            atomicAdd(dst + e * 4 + 3, v.w);
        }
    }
    __syncthreads();

    float* sh = shadows + (size_t)(blockIdx.x % R) * COMP_FLOATS + (size_t)b * MAXINS * CE;
    for (int i = threadIdx.x; i < MAXINS * CE; i += blockDim.x)
        atomicAdd(sh + i, lcomp[i]);         // 7200 atomics/block, R-way spread
}

// comp[t] = sel gather + sum of R shadows
__global__ void reduce_kernel(const float* __restrict__ shadows,
                              const int* __restrict__ batchidx,
                              const float4* __restrict__ selsrc,
                              float4* __restrict__ comp, int R) {
    int t = blockIdx.x * blockDim.x + threadIdx.x;   // over BZ*MAXINS*CE4 = 7200
    if (t >= BZ * MAXINS * CE4) return;
    int e4 = t % CE4;
    int bm = t / CE4;
    int c  = batchidx[bm];
    float4 acc = selsrc[((size_t)bm * CAND + c) * CE4 + e4];
    for (int r = 0; r < R; ++r) {
        float4 s = ((const float4*)(shadows + (size_t)r * COMP_FLOATS))[t];
        acc.x += s.x; acc.y += s.y; acc.z += s.z; acc.w += s.w;
    }
    comp[t] = acc;
}

// ---- fallback path (ws too small): round-4 direct atomics ---------------

__global__ void init_sel_kernel(const int* __restrict__ batchidx,
                                const float4* __restrict__ selsrc,
                                float4* __restrict__ comp) {
    unsigned t = blockIdx.x * blockDim.x + threadIdx.x;   // 7200
    if (t >= BZ * MAXINS * CE4) return;
    unsigned e4 = t % CE4;
    unsigned bm = t / CE4;
    int c = batchidx[bm];
    comp[bm * CE4 + e4] = selsrc[(bm * CAND + (unsigned)c) * CE4 + e4];
}

__global__ void compress_direct_kernel(const int* __restrict__ inst,
                                       const float4* __restrict__ compsrc,
                                       float* __restrict__ comp) {
    const unsigned total = BZ * PIX * CE4;
    for (unsigned t = blockIdx.x * blockDim.x + threadIdx.x; t < total;
         t += gridDim.x * blockDim.x) {
        unsigned e4 = t % CE4;
        unsigned pix = t / CE4;
        unsigned b = pix / PIX;
        int m = inst[pix];
        float4 v = compsrc[t];
        float* dst = comp + ((unsigned)(b * MAXINS + m)) * CE + e4 * 4;
        atomicAdd(dst + 0, v.x);
        atomicAdd(dst + 1, v.y);
        atomicAdd(dst + 2, v.z);
        atomicAdd(dst + 3, v.w);
    }
}

// ---- K3: inflate --------------------------------------------------------

__global__ void inflate_kernel(const int* __restrict__ inst,
                               const float4* __restrict__ comp,
                               float4* __restrict__ out) {
    const unsigned total = BZ * PIX * CE4;
    for (unsigned t = blockIdx.x * blockDim.x + threadIdx.x; t < total;
         t += gridDim.x * blockDim.x) {
        unsigned e4 = t % CE4;
        unsigned pix = t / CE4;
        unsigned b = pix / PIX;
        int m = inst[pix];
        out[t] = comp[((unsigned)(b * MAXINS + m)) * CE4 + e4];  // L2-hot gather
    }
}

extern "C" void kernel_launch(void* const* d_in, const int* in_sizes, int n_in,
                              void* d_out, int out_size, void* d_ws, size_t ws_size,
                              hipStream_t stream) {
    const int*    inst     = (const int*)d_in[0];      // (BZ,1,H,W) int32
    const float*  compsrc  = (const float*)d_in[1];    // (BZ,H,W,6,6) f32
    const int*    batchidx = (const int*)d_in[2];      // (BZ,MAXINS) int32
    const float*  selsrc   = (const float*)d_in[3];    // (BZ,MAXINS,CAND,6,6) f32
    float*        out      = (float*)d_out;            // (BZ,H,W,6,6) f32
    float*        comp     = (float*)d_ws;             // final comp: 115.2 KB @ ws[0]

    // Shadow copies live after the final comp buffer; R adapts to ws_size.
    long r_avail = (long)(ws_size / COMP_BYTES) - 1;
    int R = (int)(r_avail < 0 ? 0 : (r_avail > 16 ? 16 : r_avail));

    if (R >= 1) {
        float* shadows = comp + COMP_FLOATS;
        // K0: zero the R shadow copies (ws is NOT re-poisoned between replays)
        {
            int n4 = R * (COMP_FLOATS / 4);
            zero_kernel<<<(n4 + 255) / 256, 256, 0, stream>>>((float4*)shadows, n4);
        }
        // K2: LDS-aggregated segment-sum, replicated flush
        compress_lds_kernel<<<NBLK, 256, 0, stream>>>(inst, (const float4*)compsrc,
                                                      shadows, R);
        // K2.5: reduce shadows + fold in the batchsel gather
        {
            const int total = BZ * MAXINS * CE4;       // 7200
            reduce_kernel<<<(total + 255) / 256, 256, 0, stream>>>(
                shadows, batchidx, (const float4*)selsrc, (float4*)comp, R);
        }
    } else {
        // Fallback: direct atomics (round-4 behavior, correct but slower)
        const int total = BZ * MAXINS * CE4;
        init_sel_kernel<<<(total + 255) / 256, 256, 0, stream>>>(
            batchidx, (const float4*)selsrc, (float4*)comp);
        compress_direct_kernel<<<2048, 256, 0, stream>>>(inst, (const float4*)compsrc,
                                                         comp);
    }

    // K3: inflate comp back to per-pixel output
    inflate_kernel<<<2048, 256, 0, stream>>>(inst, (const float4*)comp, (float4*)out);
}

// Round 9
// 121.802 us; speedup vs baseline: 3.1428x; 1.0379x over previous
//
#include <hip/hip_runtime.h>

// Problem constants (from reference setup_inputs)
#define BZ 4
#define H 192
#define W 640
#define PIX (H * W)            // 122880 pixels per batch
#define MAXINS 200
#define CAND 16
#define CE 36                  // ch*cw
#define CE4 9                  // float4 groups per pixel
#define BATCH_FLOATS (MAXINS * CE)          // 7200 floats per batch
#define BATCH_F4     (BATCH_FLOATS / 4)     // 1800 float4 per batch
#define COMP_FLOATS (BZ * BATCH_FLOATS)     // 28800 floats
#define COMP_BYTES  (COMP_FLOATS * 4)       // 115200 bytes
#define LSTRIDE 37                          // padded LDS row (bank spread)
#define BPB 192                             // blocks per batch for compress
#define NBLK (BZ * BPB)                     // 768 compress blocks (~3/CU)
#define PART_BYTES ((size_t)NBLK * BATCH_FLOATS * 4)   // 22.1 MB

// =================== Path A: private non-atomic partials =================
// Replay-safe by construction: every ws byte this path reads is overwritten
// by plain stores earlier in the same call. No global atomics, no zeroing.

__global__ void compress_priv_kernel(const int* __restrict__ inst,
                                     const float4* __restrict__ compsrc,
                                     float4* __restrict__ partials) {
    __shared__ float lcomp[MAXINS * LSTRIDE];   // 29.6 KB, padded
    for (int i = threadIdx.x; i < MAXINS * LSTRIDE; i += blockDim.x) lcomp[i] = 0.f;
    __syncthreads();

    const int b   = blockIdx.x / BPB;
    const int blk = blockIdx.x % BPB;
    const unsigned base = (unsigned)b * PIX * CE4;

    for (unsigned t = blk * blockDim.x + threadIdx.x; t < PIX * CE4;
         t += BPB * blockDim.x) {
        const unsigned pix = t / CE4;
        const unsigned e4  = t - pix * CE4;
        const int m = inst[b * PIX + pix];      // 9 adjacent lanes share (L1 bcast)
        float4 v = compsrc[base + t];           // fully coalesced 16B/lane
        float* dst = lcomp + m * LSTRIDE + e4 * 4;
        atomicAdd(dst + 0, v.x);                // ds_add_f32, CU-local
        atomicAdd(dst + 1, v.y);
        atomicAdd(dst + 2, v.z);
        atomicAdd(dst + 3, v.w);
    }
    __syncthreads();

    // Store the FULL private partial (zeros included) -> every byte written.
    float4* p = partials + (size_t)blockIdx.x * BATCH_F4;
    for (int j = threadIdx.x; j < BATCH_F4; j += blockDim.x) {
        const int f = j * 4;                    // float index; CE%4==0 -> no row cross
        const int m = f / CE;
        const int k = f - m * CE;
        const float* ls = lcomp + m * LSTRIDE + k;
        p[j] = make_float4(ls[0], ls[1], ls[2], ls[3]);   // coalesced store
    }
}

// comp[t4] = sel gather + sum over the BPB partial slots of batch b
__global__ void reduce_priv_kernel(const float4* __restrict__ partials,
                                   const int* __restrict__ batchidx,
                                   const float4* __restrict__ selsrc,
                                   float4* __restrict__ comp) {
    const int t = blockIdx.x * blockDim.x + threadIdx.x;   // over 7200 float4
    if (t >= COMP_FLOATS / 4) return;
    const int e4 = t % CE4;
    const int bm = t / CE4;                    // b*MAXINS + m
    const int b  = t / BATCH_F4;
    const int j  = t - b * BATCH_F4;           // == (bm%MAXINS)*9 + e4
    const int c  = batchidx[bm];
    float4 acc = selsrc[((size_t)bm * CAND + c) * CE4 + e4];
    const float4* p = partials + (size_t)b * BPB * BATCH_F4 + j;
    #pragma unroll 8
    for (int s = 0; s < BPB; ++s) {
        float4 v = p[(size_t)s * BATCH_F4];    // independent loads -> ILP
        acc.x += v.x; acc.y += v.y; acc.z += v.z; acc.w += v.w;
    }
    comp[t] = acc;
}

// ============ Path B: shadow-atomic (device-scope hardened) ==============

__global__ void zero_shadows_kernel(float* __restrict__ p, int n) {
    for (int t = blockIdx.x * blockDim.x + threadIdx.x; t < n;
         t += gridDim.x * blockDim.x)
        __hip_atomic_store(p + t, 0.f, __ATOMIC_RELAXED, __HIP_MEMORY_SCOPE_AGENT);
}

__global__ void compress_shadow_kernel(const int* __restrict__ inst,
                                       const float4* __restrict__ compsrc,
                                       float* __restrict__ shadows, int R) {
    __shared__ float lcomp[MAXINS * LSTRIDE];
    for (int i = threadIdx.x; i < MAXINS * LSTRIDE; i += blockDim.x) lcomp[i] = 0.f;
    __syncthreads();

    const int b   = blockIdx.x / BPB;
    const int blk = blockIdx.x % BPB;
    const unsigned base = (unsigned)b * PIX * CE4;

    for (unsigned t = blk * blockDim.x + threadIdx.x; t < PIX * CE4;
         t += BPB * blockDim.x) {
        const unsigned pix = t / CE4;
        const unsigned e4  = t - pix * CE4;
        const int m = inst[b * PIX + pix];
        float4 v = compsrc[base + t];
        float* dst = lcomp + m * LSTRIDE + e4 * 4;
        atomicAdd(dst + 0, v.x);
        atomicAdd(dst + 1, v.y);
        atomicAdd(dst + 2, v.z);
        atomicAdd(dst + 3, v.w);
    }
    __syncthreads();

    float* sh = shadows + (size_t)(blockIdx.x % R) * COMP_FLOATS
                        + (size_t)b * BATCH_FLOATS;
    for (int i = threadIdx.x; i < BATCH_FLOATS; i += blockDim.x) {
        const int m = i / CE;
        const int k = i - m * CE;
        atomicAdd(sh + i, lcomp[m * LSTRIDE + k]);
    }
}

__global__ void reduce_shadow_kernel(const float* __restrict__ shadows,
                                     const int* __restrict__ batchidx,
                                     const float* __restrict__ selsrc,
                                     float* __restrict__ comp, int R) {
    const int i = blockIdx.x * blockDim.x + threadIdx.x;   // over 28800 floats
    if (i >= COMP_FLOATS) return;
    const int k  = i % CE;
    const int bm = i / CE;
    const int c  = batchidx[bm];
    float acc = selsrc[((size_t)bm * CAND + c) * CE + k];
    for (int r = 0; r < R; ++r)
        acc += __hip_atomic_load(shadows + (size_t)r * COMP_FLOATS + i,
                                 __ATOMIC_RELAXED, __HIP_MEMORY_SCOPE_AGENT);
    comp[i] = acc;
}

// ============ Path C: direct atomics (minimal ws) ========================

__global__ void init_sel_kernel(const int* __restrict__ batchidx,
                                const float4* __restrict__ selsrc,
                                float4* __restrict__ comp) {
    unsigned t = blockIdx.x * blockDim.x + threadIdx.x;   // 7200
    if (t >= BZ * MAXINS * CE4) return;
    unsigned e4 = t % CE4;
    unsigned bm = t / CE4;
    int c = batchidx[bm];
    comp[bm * CE4 + e4] = selsrc[(bm * CAND + (unsigned)c) * CE4 + e4];
}

__global__ void compress_direct_kernel(const int* __restrict__ inst,
                                       const float4* __restrict__ compsrc,
                                       float* __restrict__ comp) {
    const unsigned total = BZ * PIX * CE4;
    for (unsigned t = blockIdx.x * blockDim.x + threadIdx.x; t < total;
         t += gridDim.x * blockDim.x) {
        unsigned e4 = t % CE4;
        unsigned pix = t / CE4;
        unsigned b = pix / PIX;
        int m = inst[pix];
        float4 v = compsrc[t];
        float* dst = comp + ((unsigned)(b * MAXINS + m)) * CE + e4 * 4;
        atomicAdd(dst + 0, v.x);
        atomicAdd(dst + 1, v.y);
        atomicAdd(dst + 2, v.z);
        atomicAdd(dst + 3, v.w);
    }
}

// ============ K3: inflate ================================================

__global__ void inflate_kernel(const int* __restrict__ inst,
                               const float4* __restrict__ comp,
                               float4* __restrict__ out) {
    const unsigned total = BZ * PIX * CE4;
    for (unsigned t = blockIdx.x * blockDim.x + threadIdx.x; t < total;
         t += gridDim.x * blockDim.x) {
        unsigned e4 = t % CE4;
        unsigned pix = t / CE4;
        unsigned b = pix / PIX;
        int m = inst[pix];
        out[t] = comp[((unsigned)(b * MAXINS + m)) * CE4 + e4];  // L2-hot gather
    }
}

extern "C" void kernel_launch(void* const* d_in, const int* in_sizes, int n_in,
                              void* d_out, int out_size, void* d_ws, size_t ws_size,
                              hipStream_t stream) {
    const int*    inst     = (const int*)d_in[0];      // (BZ,1,H,W) int32
    const float*  compsrc  = (const float*)d_in[1];    // (BZ,H,W,6,6) f32
    const int*    batchidx = (const int*)d_in[2];      // (BZ,MAXINS) int32
    const float*  selsrc   = (const float*)d_in[3];    // (BZ,MAXINS,CAND,6,6) f32
    float*        out      = (float*)d_out;            // (BZ,H,W,6,6) f32
    float*        comp     = (float*)d_ws;             // final comp: 115.2 KB @ ws[0]

    if (ws_size >= (size_t)COMP_BYTES + PART_BYTES) {
        // --- Path A: private partials, no atomics, no zeroing ---
        float4* partials = (float4*)(comp + COMP_FLOATS);
        compress_priv_kernel<<<NBLK, 256, 0, stream>>>(inst, (const float4*)compsrc,
                                                       partials);
        reduce_priv_kernel<<<(COMP_FLOATS / 4 + 255) / 256, 256, 0, stream>>>(
            partials, batchidx, (const float4*)selsrc, (float4*)comp);
    } else if (ws_size >= 2 * (size_t)COMP_BYTES) {
        // --- Path B: shadow atomics, device-scope-coherent zero/read ---
        long r_avail = (long)(ws_size / COMP_BYTES) - 1;
        int R = (int)(r_avail > 16 ? 16 : r_avail);
        float* shadows = comp + COMP_FLOATS;
        int n = R * COMP_FLOATS;
        zero_shadows_kernel<<<(n + 255) / 256, 256, 0, stream>>>(shadows, n);
        compress_shadow_kernel<<<NBLK, 256, 0, stream>>>(inst, (const float4*)compsrc,
                                                         shadows, R);
        reduce_shadow_kernel<<<(COMP_FLOATS + 255) / 256, 256, 0, stream>>>(
            shadows, batchidx, selsrc, comp, R);
    } else {
        // --- Path C: direct atomics into comp ---
        const int total = BZ * MAXINS * CE4;
        init_sel_kernel<<<(total + 255) / 256, 256, 0, stream>>>(
            batchidx, (const float4*)selsrc, (float4*)comp);
        compress_direct_kernel<<<2048, 256, 0, stream>>>(inst, (const float4*)compsrc,
                                                         comp);
    }

    // K3: inflate comp back to per-pixel output
    inflate_kernel<<<2048, 256, 0, stream>>>(inst, (const float4*)comp, (float4*)out);
}